// Round 1
// baseline (2882.055 us; speedup 1.0000x reference)
//
#include <hip/hip_runtime.h>
#include <math.h>

#define D 64
#define NEG 0.2f
#define WPB 4              // waves per block
#define BLK (WPB * 64)

__device__ __forceinline__ float lrelu(float v) { return v > 0.f ? v : NEG * v; }

// ---------------- CSR build ----------------

__global__ __launch_bounds__(256) void k_count(
    const int* __restrict__ e0, const int* __restrict__ e1,
    const int* __restrict__ e2, const int* __restrict__ e3,
    int* __restrict__ counts, int E, int N)
{
    int r = blockIdx.y;
    const int* ep = (r == 0) ? e0 : (r == 1) ? e1 : (r == 2) ? e2 : e3;
    int i = blockIdx.x * 256 + threadIdx.x;
    if (i < E) {
        int d = ep[E + i];            // dst row
        atomicAdd(&counts[(size_t)r * N + d], 1);
    }
}

// per-block exclusive scan of counts; block sums out
__global__ __launch_bounds__(256) void k_scanA(
    const int* __restrict__ counts, int* __restrict__ prefix,
    int* __restrict__ bsums, int N, int nb)
{
    int r = blockIdx.y;
    __shared__ int sh[256];
    int t = threadIdx.x;
    int i = blockIdx.x * 256 + t;
    int v = (i < N) ? counts[(size_t)r * N + i] : 0;
    sh[t] = v;
    __syncthreads();
    for (int off = 1; off < 256; off <<= 1) {
        int add = (t >= off) ? sh[t - off] : 0;
        __syncthreads();
        sh[t] += add;
        __syncthreads();
    }
    if (i < N) prefix[(size_t)r * (N + 1) + i] = sh[t] - v;   // exclusive
    if (t == 255) bsums[r * nb + blockIdx.x] = sh[255];
}

// scan the block sums (nb <= 512)
__global__ __launch_bounds__(512) void k_scanB(int* __restrict__ bsums, int nb)
{
    int r = blockIdx.y;
    __shared__ int sh[512];
    int t = threadIdx.x;
    int v = (t < nb) ? bsums[r * nb + t] : 0;
    sh[t] = v;
    __syncthreads();
    for (int off = 1; off < 512; off <<= 1) {
        int add = (t >= off) ? sh[t - off] : 0;
        __syncthreads();
        sh[t] += add;
        __syncthreads();
    }
    if (t < nb) bsums[r * nb + t] = sh[t] - v;                // exclusive
}

__global__ __launch_bounds__(256) void k_scanC(
    int* __restrict__ prefix, const int* __restrict__ bsums,
    int* __restrict__ cursor, int N, int nb, int E)
{
    int r = blockIdx.y;
    int i = blockIdx.x * 256 + threadIdx.x;
    if (i < N) {
        int v = prefix[(size_t)r * (N + 1) + i] + bsums[r * nb + blockIdx.x];
        prefix[(size_t)r * (N + 1) + i] = v;
        cursor[(size_t)r * N + i] = v;
    }
    if (blockIdx.x == 0 && threadIdx.x == 0) prefix[(size_t)r * (N + 1) + N] = E;
}

__global__ __launch_bounds__(256) void k_fill(
    const int* __restrict__ e0, const int* __restrict__ e1,
    const int* __restrict__ e2, const int* __restrict__ e3,
    int* __restrict__ cursor, int* __restrict__ srcs, int E, int N)
{
    int r = blockIdx.y;
    const int* ep = (r == 0) ? e0 : (r == 1) ? e1 : (r == 2) ? e2 : e3;
    int i = blockIdx.x * 256 + threadIdx.x;
    if (i < E) {
        int s = ep[i];
        int d = ep[E + i];
        int pos = atomicAdd(&cursor[(size_t)r * N + d], 1);
        srcs[(size_t)r * E + pos] = s;
    }
}

// ---------------- per-layer compute ----------------

// h = x @ W ; a_src = h . att_s ; a_dst = h . att_d   (one wave per node)
__global__ __launch_bounds__(BLK) void k_gemm_h(
    const float* __restrict__ x, const float* __restrict__ W,
    const float* __restrict__ att_s, const float* __restrict__ att_d,
    float* __restrict__ h, float* __restrict__ a_s, float* __restrict__ a_d, int N)
{
    int lane = threadIdx.x & 63;
    int n = blockIdx.x * WPB + (threadIdx.x >> 6);
    if (n >= N) return;
    float xv = x[(size_t)n * D + lane];
    float acc = 0.f;
#pragma unroll
    for (int k = 0; k < D; k++) acc = fmaf(__shfl(xv, k), W[k * D + lane], acc);
    h[(size_t)n * D + lane] = acc;
    float ps = acc * att_s[lane];
    float pd = acc * att_d[lane];
#pragma unroll
    for (int off = 32; off; off >>= 1) {
        ps += __shfl_xor(ps, off);
        pd += __shfl_xor(pd, off);
    }
    if (lane == 0) { a_s[n] = ps; a_d[n] = pd; }
}

// hidden_pre[n,c] = b1[c] + sum_k x[n,k] * W1[k*64+c]    (x-part of MLP1)
__global__ __launch_bounds__(BLK) void k_mlp1x(
    const float* __restrict__ x, const float* __restrict__ W1,
    const float* __restrict__ b1, float* __restrict__ hp, int N)
{
    int lane = threadIdx.x & 63;
    int n = blockIdx.x * WPB + (threadIdx.x >> 6);
    if (n >= N) return;
    float xv = x[(size_t)n * D + lane];
    float acc = b1[lane];
#pragma unroll
    for (int k = 0; k < D; k++) acc = fmaf(__shfl(xv, k), W1[k * D + lane], acc);
    hp[(size_t)n * D + lane] = acc;
}

// GAT aggregation (online softmax, gather CSR) + fused MLP1 slice accumulation.
// One wave per dst node; lane = feature dim.
__global__ __launch_bounds__(BLK) void k_agg(
    const float* __restrict__ h, const float* __restrict__ a_src,
    const float* __restrict__ a_dst, const int* __restrict__ starts,
    const int* __restrict__ srcs, const float* __restrict__ bias,
    const float* __restrict__ W1r, float* __restrict__ hp, int N)
{
    int lane = threadIdx.x & 63;
    int d = blockIdx.x * WPB + (threadIdx.x >> 6);
    if (d >= N) return;

    int base = starts[d];
    int cnt = starts[d + 1] - base;
    float ad = a_dst[d];
    float alpha_self = lrelu(a_src[d] + ad);

    // phase 1: max over edges + self-loop
    bool has = lane < cnt;
    int s0 = has ? srcs[base + lane] : 0;
    float a0 = has ? lrelu(a_src[s0] + ad) : -1e30f;
    float m = fmaxf(alpha_self, a0);
    for (int jj = lane + 64; jj < cnt; jj += 64) {
        int s = srcs[base + jj];
        m = fmaxf(m, lrelu(a_src[s] + ad));
    }
#pragma unroll
    for (int off = 32; off; off >>= 1) m = fmaxf(m, __shfl_xor(m, off));

    // phase 2: online-softmax weighted sum
    float e_self = __expf(alpha_self - m);
    float z = e_self;
    float acc = e_self * h[(size_t)d * D + lane];

    float e0 = has ? __expf(a0 - m) : 0.f;
    int lim = cnt < 64 ? cnt : 64;
    for (int t = 0; t < lim; t++) {
        float et = __shfl(e0, t);
        int st = __shfl(s0, t);
        z += et;
        acc = fmaf(et, h[(size_t)st * D + lane], acc);
    }
    for (int j0 = 64; j0 < cnt; j0 += 64) {
        int jj = j0 + lane;
        bool h2 = jj < cnt;
        int s = h2 ? srcs[base + jj] : 0;
        float ee = h2 ? __expf(lrelu(a_src[s] + ad) - m) : 0.f;
        int lim2 = (cnt - j0) < 64 ? (cnt - j0) : 64;
        for (int t = 0; t < lim2; t++) {
            float et = __shfl(ee, t);
            int st = __shfl(s, t);
            z += et;
            acc = fmaf(et, h[(size_t)st * D + lane], acc);
        }
    }

    float g = acc / z + bias[lane];   // GAT output feature `lane` for node d

    // fused MLP1 slice: hp[d,c] += sum_k g_k * W1r[k*64+c]
    float hpacc = 0.f;
#pragma unroll
    for (int k = 0; k < D; k++) hpacc = fmaf(__shfl(g, k), W1r[k * D + lane], hpacc);
    hp[(size_t)d * D + lane] += hpacc;
}

// x_out[n,c] = b2[c] + sum_k tanh(hp[n,k]) * W2[k*64+c]
__global__ __launch_bounds__(BLK) void k_mlp2(
    const float* __restrict__ hp, const float* __restrict__ W2,
    const float* __restrict__ b2, float* __restrict__ xout, int N)
{
    int lane = threadIdx.x & 63;
    int n = blockIdx.x * WPB + (threadIdx.x >> 6);
    if (n >= N) return;
    float hv = tanhf(hp[(size_t)n * D + lane]);
    float acc = b2[lane];
#pragma unroll
    for (int k = 0; k < D; k++) acc = fmaf(__shfl(hv, k), W2[k * D + lane], acc);
    xout[(size_t)n * D + lane] = acc;
}

// ---------------- launch ----------------

extern "C" void kernel_launch(void* const* d_in, const int* in_sizes, int n_in,
                              void* d_out, int out_size, void* d_ws, size_t ws_size,
                              hipStream_t stream)
{
    const float* x    = (const float*)d_in[0];
    const int*   e0   = (const int*)d_in[1];
    const int*   e1   = (const int*)d_in[2];
    const int*   e2   = (const int*)d_in[3];
    const int*   e3   = (const int*)d_in[4];
    const float* gatW = (const float*)d_in[5];   // (2,4,64,64)
    const float* atS  = (const float*)d_in[6];   // (2,4,64)
    const float* atD  = (const float*)d_in[7];
    const float* gatB = (const float*)d_in[8];
    const float* W1   = (const float*)d_in[9];   // (2,320,64)
    const float* b1   = (const float*)d_in[10];  // (2,64)
    const float* W2   = (const float*)d_in[11];  // (2,64,64)
    const float* b2   = (const float*)d_in[12];  // (2,64)
    float* out = (float*)d_out;

    const int N = in_sizes[0] / D;
    const int E = in_sizes[1] / 2;

    // workspace layout
    size_t off = 0;
    auto alloc = [&](size_t bytes) { size_t o = off; off = (off + bytes + 255) & ~(size_t)255; return o; };
    float* h      = (float*)((char*)d_ws + alloc((size_t)N * D * 4));
    float* hp     = (float*)((char*)d_ws + alloc((size_t)N * D * 4));
    float* xnext  = (float*)((char*)d_ws + alloc((size_t)N * D * 4));
    float* a_s    = (float*)((char*)d_ws + alloc((size_t)N * 4));
    float* a_d    = (float*)((char*)d_ws + alloc((size_t)N * 4));
    int*   counts = (int*)((char*)d_ws + alloc((size_t)4 * N * 4));
    int*   prefix = (int*)((char*)d_ws + alloc((size_t)4 * (N + 1) * 4));
    int*   cursor = (int*)((char*)d_ws + alloc((size_t)4 * N * 4));
    int nb = (N + 255) / 256;
    int*   bsums  = (int*)((char*)d_ws + alloc((size_t)4 * nb * 4));
    int*   srcs   = (int*)((char*)d_ws + alloc((size_t)4 * E * 4));
    (void)ws_size;

    const int nodeBlocks = (N + WPB - 1) / WPB;
    const int edgeBlocks = (E + 255) / 256;

    // ---- CSR build (edges identical for both layers) ----
    hipMemsetAsync(counts, 0, (size_t)4 * N * 4, stream);
    k_count<<<dim3(edgeBlocks, 4), 256, 0, stream>>>(e0, e1, e2, e3, counts, E, N);
    k_scanA<<<dim3(nb, 4), 256, 0, stream>>>(counts, prefix, bsums, N, nb);
    k_scanB<<<dim3(1, 4), 512, 0, stream>>>(bsums, nb);
    k_scanC<<<dim3(nb, 4), 256, 0, stream>>>(prefix, bsums, cursor, N, nb, E);
    k_fill<<<dim3(edgeBlocks, 4), 256, 0, stream>>>(e0, e1, e2, e3, cursor, srcs, E, N);

    // ---- layers ----
    for (int l = 0; l < 2; l++) {
        const float* xin = (l == 0) ? x : xnext;
        float* xout = (l == 1) ? out : xnext;
        const float* W1l = W1 + (size_t)l * 5 * D * D;

        k_mlp1x<<<nodeBlocks, BLK, 0, stream>>>(xin, W1l, b1 + l * D, hp, N);

        for (int r = 0; r < 4; r++) {
            int lr = l * 4 + r;
            k_gemm_h<<<nodeBlocks, BLK, 0, stream>>>(
                xin, gatW + (size_t)lr * D * D, atS + (size_t)lr * D, atD + (size_t)lr * D,
                h, a_s, a_d, N);
            k_agg<<<nodeBlocks, BLK, 0, stream>>>(
                h, a_s, a_d, prefix + (size_t)r * (N + 1), srcs + (size_t)r * E,
                gatB + (size_t)lr * D, W1l + (size_t)(D + r * D) * D, hp, N);
        }

        k_mlp2<<<nodeBlocks, BLK, 0, stream>>>(hp, W2 + (size_t)l * D * D, b2 + l * D, xout, N);
    }
}